// Round 9
// baseline (242.682 us; speedup 1.0000x reference)
//
#include <hip/hip_runtime.h>
#include <hip/hip_bf16.h>
#include <stdint.h>

#define NN 50000       // nodes
#define NE 800000      // edges
#define IN_F 128
#define H_F 256
#define M_PAD 50048    // 782 * 64

typedef unsigned int uint32;
typedef unsigned short u16;
typedef __attribute__((ext_vector_type(8))) short short8;
typedef __attribute__((ext_vector_type(4))) float floatx4;

__device__ __forceinline__ float bf16_to_f(uint32 bits16) {
    union { uint32 u; float f; } c; c.u = bits16 << 16; return c.f;
}
__device__ __forceinline__ uint32 f_to_bf16(float f) {
    union { float f; uint32 u; } c; c.f = f;
    uint32 u = c.u;
    u += 0x7FFFu + ((u >> 16) & 1u);   // round-to-nearest-even
    return u >> 16;
}

// async global->LDS, 16B per lane. LDS dest must be wave-uniform base (HW adds lane*16).
__device__ __forceinline__ void gload_lds16(const void* g, void* l) {
    __builtin_amdgcn_global_load_lds((__attribute__((address_space(1))) void*)g,
                                     (__attribute__((address_space(3))) void*)l,
                                     16, 0, 0);
}

// ---------------- fused prep: cast feats + transpose/stack weights + zero-rows
//                  + degree count WITH per-edge rank (atomic return stored coalesced)
#define PREP_A (NN * IN_F / 4)
#define PREP_B (256 * 256)
#define PREP_C (256 * 512)
#define PREP_Z (16 + 32)            // 16B-granule zero stores: 256B (inA) + 512B (h)
#define PREP_TOTAL (PREP_A + PREP_B + PREP_C + PREP_Z + NE)

__global__ void prep_kernel(const float* __restrict__ in_feat, u16* __restrict__ inA,
                            const float* __restrict__ Ws1, const float* __restrict__ Wn1,
                            u16* __restrict__ BT1,
                            const float* __restrict__ Ws2, const float* __restrict__ Wn2,
                            u16* __restrict__ BT2,
                            u16* __restrict__ h,
                            const int* __restrict__ dst, int* __restrict__ counts,
                            int* __restrict__ rank) {
    int id = blockIdx.x * 256 + threadIdx.x;
    if (id < PREP_A) {
        float4 v = *((const float4*)in_feat + id);
        ushort4 o;
        o.x = (u16)f_to_bf16(v.x); o.y = (u16)f_to_bf16(v.y);
        o.z = (u16)f_to_bf16(v.z); o.w = (u16)f_to_bf16(v.w);
        *((ushort4*)inA + id) = o;
        return;
    }
    id -= PREP_A;
    if (id < PREP_B) {              // BT1[n][k], Ktot=256, K1=128
        int n = id >> 8, k = id & 255;
        float v = (k < 128) ? Ws1[(size_t)k * H_F + n] : Wn1[(size_t)(k - 128) * H_F + n];
        BT1[(size_t)n * 256 + k] = (u16)f_to_bf16(v);
        return;
    }
    id -= PREP_B;
    if (id < PREP_C) {              // BT2[n][k], Ktot=512, K1=256
        int n = id >> 9, k = id & 511;
        float v = (k < 256) ? Ws2[(size_t)k * H_F + n] : Wn2[(size_t)(k - 256) * H_F + n];
        BT2[(size_t)n * 512 + k] = (u16)f_to_bf16(v);
        return;
    }
    id -= PREP_C;
    if (id < PREP_Z) {              // zero row NN of inA (256B) and h (512B)
        uint4 z = {0u, 0u, 0u, 0u};
        if (id < 16) *((uint4*)(inA + (size_t)NN * IN_F) + id) = z;
        else         *((uint4*)(h   + (size_t)NN * H_F)  + (id - 16)) = z;
        return;
    }
    id -= PREP_Z;
    if (id < NE) rank[id] = atomicAdd(&counts[dst[id]], 1);
}

// ---------------- CSR build ----------------

__global__ void scan1_kernel(const int* __restrict__ counts, int* __restrict__ row_start,
                             int* __restrict__ partials, int n) {
    __shared__ int s[256];
    int t = threadIdx.x;
    int i = blockIdx.x * 256 + t;
    int x = (i < n) ? counts[i] : 0;
    s[t] = x;
    __syncthreads();
    for (int off = 1; off < 256; off <<= 1) {
        int y = (t >= off) ? s[t - off] : 0;
        __syncthreads();
        s[t] += y;
        __syncthreads();
    }
    if (i < n) row_start[i] = s[t] - x;            // block-local exclusive
    if (t == 255) partials[blockIdx.x] = s[255];   // block total
}

// folds old scan2: each block re-scans the block-total array itself (196 ints)
__global__ void scan3_kernel(int* __restrict__ row_start, const int* __restrict__ partials,
                             const int* __restrict__ counts,
                             float* __restrict__ deg_inv, int n, int nparts) {
    __shared__ int s[256];
    int t = threadIdx.x;
    int x = (t < nparts) ? partials[t] : 0;
    s[t] = x;
    __syncthreads();
    for (int off = 1; off < 256; off <<= 1) {
        int y = (t >= off) ? s[t - off] : 0;
        __syncthreads();
        s[t] += y;
        __syncthreads();
    }
    int boff = blockIdx.x ? s[blockIdx.x - 1] : 0;   // exclusive prefix of this block
    int i = blockIdx.x * 256 + t;
    if (i >= n) return;
    row_start[i] += boff;
    int c = counts[i];
    deg_inv[i] = 1.0f / (float)(c > 1 ? c : 1);
}

// atomic-free: position = row_start[dst] + precomputed rank
__global__ void scatter_kernel(const int* __restrict__ src, const int* __restrict__ dst,
                               const int* __restrict__ rank, const int* __restrict__ row_start,
                               int* __restrict__ csr_src) {
    int e = blockIdx.x * 256 + threadIdx.x;
    if (e < NE) {
        int d = dst[e];
        csr_src[row_start[d] + rank[e]] = src[e];
    }
}

// ---------------- fused layer: agg (64 nodes -> LDS) + GEMM (64 x 256) --------------
// K1: input feature dim (128 layer1, 256 layer2). Aft: [M_PAD(+pad)][K1] bf16 table
// (row NN pre-zeroed). BT: [256][2*K1] stacked W_self/W_neigh transposed.
// Phase 1: wave w aggregates nodes brow+w*16..+15 (R4-proven gather: indices loaded
// once, broadcast via shfl, U unconditional dwordx4 loads in flight), writes bf16 mean
// rows into LDS AN tile with XOR swizzle (byte = r*ROWB + (cb ^ ((r&7)<<4))).
// Phase 2: R8-proven GEMM; self K-tiles stage A from global via gload_lds (inverse-
// swizzled source, rule #21), neigh K-tiles read AN directly. B restaged per K-tile
// (BT is L2-resident). 2 blocks/CU -> sibling block's MFMA overlaps this block's gather.
template<int K1, int RELU_BF16>
__global__ __launch_bounds__(256)
void fused_kernel(const u16* __restrict__ Aft, const int* __restrict__ csr_src,
                  const int* __restrict__ row_start, const int* __restrict__ counts,
                  const float* __restrict__ deg_inv,
                  const u16* __restrict__ BT, const float* __restrict__ bias,
                  void* __restrict__ outp) {
    constexpr int ROWB = K1 * 2;           // bytes per A row
    constexpr int ANB  = 64 * ROWB;        // AN tile bytes (16KB / 32KB)
    constexpr int DW   = K1 / 2;           // u32 words per row
    constexpr int LPR  = DW / 4;           // lanes per row: 16 or 32
    constexpr int EPW  = 64 / LPR;         // edges per batch-slot: 4 or 2
    constexpr int U    = (K1 == 128) ? 8 : 16;
    constexpr int EPI  = EPW * U;          // 32 edges per batch
    constexpr int T1   = K1 / 64;          // self K-tiles
    constexpr int NT   = 2 * T1;

    __shared__ __attribute__((aligned(16))) char lds[ANB + 8192 + 32768];
    // [0,ANB) AN | [ANB,ANB+8192) Aself tile | [ANB+8192, +32768) B tile
    constexpr int LAS = 0 + ANB;
    constexpr int LB  = ANB + 8192;

    const int tid = threadIdx.x;
    const int w = tid >> 6, lane = tid & 63;
    const int brow = blockIdx.x * 64;
    const int l15 = lane & 15, l7 = lane & 7, kg = lane >> 4;
    const int g  = lane / LPR;
    const int wo = (lane % LPR) * 4;       // word offset within row
    const uint32* ftw = (const uint32*)Aft + wo;

    // ---- phase 1: aggregate 16 nodes per wave into AN ----
    for (int t = 0; t < 16; ++t) {
        const int r = w * 16 + t;
        const int node = brow + r;
        int start = 0, cnt = 0; float dinv = 1.0f;
        if (node < NN) { start = row_start[node]; cnt = counts[node]; dinv = deg_inv[node]; }

        int clampe = cnt > 0 ? cnt - 1 : 0;
        int myidx = csr_src[start + (lane < clampe ? lane : clampe)];
        if (lane >= cnt) myidx = NN;       // pre-zeroed row

        float acc[8] = {};
        const int nb = cnt < 64 ? cnt : 64;
        for (int j = 0; j < nb; j += EPI) {
            uint4 x_[U];
#pragma unroll
            for (int u = 0; u < U; ++u) {
                int idx = __shfl(myidx, j + u * EPW + g);   // <= 63 always
                x_[u] = *(const uint4*)(ftw + (size_t)idx * DW);
            }
#pragma unroll
            for (int u = 0; u < U; ++u) {
                acc[0] += bf16_to_f(x_[u].x & 0xFFFFu); acc[1] += bf16_to_f(x_[u].x >> 16);
                acc[2] += bf16_to_f(x_[u].y & 0xFFFFu); acc[3] += bf16_to_f(x_[u].y >> 16);
                acc[4] += bf16_to_f(x_[u].z & 0xFFFFu); acc[5] += bf16_to_f(x_[u].z >> 16);
                acc[6] += bf16_to_f(x_[u].w & 0xFFFFu); acc[7] += bf16_to_f(x_[u].w >> 16);
            }
        }
        for (int j = 64; j < cnt; j += EPW) {   // rare tail: degree > 64
            int e = j + g;
            int idx = (e < cnt) ? csr_src[start + e] : NN;
            uint4 x = *(const uint4*)(ftw + (size_t)idx * DW);
            acc[0] += bf16_to_f(x.x & 0xFFFFu); acc[1] += bf16_to_f(x.x >> 16);
            acc[2] += bf16_to_f(x.y & 0xFFFFu); acc[3] += bf16_to_f(x.y >> 16);
            acc[4] += bf16_to_f(x.z & 0xFFFFu); acc[5] += bf16_to_f(x.z >> 16);
            acc[6] += bf16_to_f(x.w & 0xFFFFu); acc[7] += bf16_to_f(x.w >> 16);
        }
#pragma unroll
        for (int k = 0; k < 8; ++k) {
            if (LPR <= 16) acc[k] += __shfl_xor(acc[k], 16);
            acc[k] += __shfl_xor(acc[k], 32);
        }
        if (g == 0) {
            uint4 o;
            o.x = f_to_bf16(acc[0] * dinv) | (f_to_bf16(acc[1] * dinv) << 16);
            o.y = f_to_bf16(acc[2] * dinv) | (f_to_bf16(acc[3] * dinv) << 16);
            o.z = f_to_bf16(acc[4] * dinv) | (f_to_bf16(acc[5] * dinv) << 16);
            o.w = f_to_bf16(acc[6] * dinv) | (f_to_bf16(acc[7] * dinv) << 16);
            int cb = wo * 4;               // byte col within row
            *(uint4*)&lds[r * ROWB + (cb ^ ((r & 7) << 4))] = o;
        }
    }
    __syncthreads();

    // ---- phase 2: GEMM ----
    const int srow = w * 8 + (lane >> 3);  // staging row within 32-row issue group
    const int scb = (lane & 7) * 16;       // staging byte-col slot
    const size_t sB = (size_t)(2 * K1) * 2;   // bytes per BT row

    floatx4 acc2[4][4] = {};
    const char* Ab = (const char*)Aft + (size_t)brow * ROWB;

    for (int kt = 0; kt < NT; ++kt) {
        if (kt < T1) {
#pragma unroll
            for (int i = 0; i < 2; ++i) {  // Aself: 64 rows x 128B
                int row = i * 32 + srow;
                const char* gp = Ab + (size_t)row * ROWB + kt * 128 + (scb ^ ((row & 7) << 4));
                gload_lds16(gp, &lds[LAS + i * 4096 + w * 1024]);
            }
        }
#pragma unroll
        for (int i = 0; i < 8; ++i) {      // B: all 256 BT rows x 128B
            int row = i * 32 + srow;
            const char* gp = (const char*)BT + (size_t)row * sB + kt * 128 + (scb ^ ((row & 7) << 4));
            gload_lds16(gp, &lds[LB + i * 4096 + w * 1024]);
        }
        __syncthreads();
#pragma unroll
        for (int kk = 0; kk < 2; ++kk) {
            const int cbyte = kk * 64 + kg * 16;
            short8 a[4], b[4];
            if (kt < T1) {
#pragma unroll
                for (int m = 0; m < 4; ++m)
                    a[m] = *(const short8*)&lds[LAS + (m * 16 + l15) * 128 + (cbyte ^ (l7 << 4))];
            } else {
#pragma unroll
                for (int m = 0; m < 4; ++m) {
                    int r = m * 16 + l15;
                    a[m] = *(const short8*)&lds[r * ROWB + (((kt - T1) * 128 + cbyte) ^ (l7 << 4))];
                }
            }
#pragma unroll
            for (int n = 0; n < 4; ++n) {
                int rb = w * 64 + n * 16 + l15;
                b[n] = *(const short8*)&lds[LB + rb * 128 + (cbyte ^ (l7 << 4))];
            }
#pragma unroll
            for (int m = 0; m < 4; ++m)
#pragma unroll
                for (int n = 0; n < 4; ++n)
                    acc2[m][n] = __builtin_amdgcn_mfma_f32_16x16x32_bf16(a[m], b[n], acc2[m][n], 0, 0, 0);
        }
        __syncthreads();
    }

    const int ocol0 = w * 64;
#pragma unroll
    for (int m = 0; m < 4; ++m) {
#pragma unroll
        for (int j = 0; j < 4; ++j) {
            int row = brow + m * 16 + kg * 4 + j;
            if (row < NN) {
#pragma unroll
                for (int n = 0; n < 4; ++n) {
                    int col = ocol0 + n * 16 + l15;
                    float v = acc2[m][n][j] + bias[col];
                    if (RELU_BF16) {
                        v = fmaxf(v, 0.0f);
                        ((u16*)outp)[(size_t)row * H_F + col] = (u16)f_to_bf16(v);
                    } else {
                        ((float*)outp)[(size_t)row * H_F + col] = v;
                    }
                }
            }
        }
    }
}

// ---------------- launch ----------------

extern "C" void kernel_launch(void* const* d_in, const int* in_sizes, int n_in,
                              void* d_out, int out_size, void* d_ws, size_t ws_size,
                              hipStream_t stream) {
    const float* in_feat  = (const float*)d_in[0];
    const int*   src      = (const int*)d_in[1];
    const int*   dst      = (const int*)d_in[2];
    const float* W_self1  = (const float*)d_in[3];
    const float* W_neigh1 = (const float*)d_in[4];
    const float* b1       = (const float*)d_in[5];
    const float* W_self2  = (const float*)d_in[6];
    const float* W_neigh2 = (const float*)d_in[7];
    const float* b2       = (const float*)d_in[8];
    float* out = (float*)d_out;

    char* p = (char*)d_ws;
    auto alloc = [&](size_t bytes) { char* r = p; p += (bytes + 255) & ~(size_t)255; return r; };
    int*   counts    = (int*)alloc((size_t)NN * 4);
    int*   row_start = (int*)alloc((size_t)NN * 4);
    int*   partials  = (int*)alloc(256 * 4);
    float* deg_inv   = (float*)alloc((size_t)NN * 4);
    int*   rank      = (int*)alloc((size_t)NE * 4);
    int*   csr_src   = (int*)alloc((size_t)NE * 4 + 256);
    u16*   inA       = (u16*)alloc((size_t)M_PAD * IN_F * 2);
    u16*   h         = (u16*)alloc((size_t)M_PAD * H_F * 2);
    u16*   BT1       = (u16*)alloc((size_t)256 * 256 * 2);
    u16*   BT2       = (u16*)alloc((size_t)256 * 512 * 2);

    hipMemsetAsync(counts, 0, (size_t)NN * 4, stream);

    prep_kernel<<<(PREP_TOTAL + 255) / 256, 256, 0, stream>>>(
        in_feat, inA, W_self1, W_neigh1, BT1, W_self2, W_neigh2, BT2, h, dst, counts, rank);

    const int SB = (NN + 255) / 256;   // 196
    scan1_kernel<<<SB, 256, 0, stream>>>(counts, row_start, partials, NN);
    scan3_kernel<<<SB, 256, 0, stream>>>(row_start, partials, counts, deg_inv, NN, SB);
    scatter_kernel<<<(NE + 255) / 256, 256, 0, stream>>>(src, dst, rank, row_start, csr_src);

    // layer 1: agg(inA) + GEMM -> h (bf16, relu)
    fused_kernel<IN_F, 1><<<M_PAD / 64, 256, 0, stream>>>(
        inA, csr_src, row_start, counts, deg_inv, BT1, b1, (void*)h);
    // layer 2: agg(h) + GEMM -> out (f32)
    fused_kernel<H_F, 0><<<M_PAD / 64, 256, 0, stream>>>(
        h, csr_src, row_start, counts, deg_inv, BT2, b2, (void*)out);
}